// Round 17
// baseline (263.268 us; speedup 1.0000x reference)
//
#include <hip/hip_runtime.h>
#include <math.h>
#include <stdint.h>

#define NFL   16384
#define NCC   55      // base cells: ix,iy in 0..6 -> ixiy = ix*8+iy in 0..54
#define PADQ  128     // bucket pad quantum (=2 conv chunks per block)

struct EdgeData { int src; int ixiy; float fx; float fy; };

typedef _Float16 half8 __attribute__((ext_vector_type(8)));
typedef __attribute__((ext_vector_type(4))) float f32x4;

__device__ __forceinline__ float frelu(float x){ return x > 0.f ? x : 0.f; }
__device__ __forceinline__ unsigned short f2bf(float f){
    unsigned int u = __float_as_uint(f);
    unsigned int r = (u + 0x7FFFu + ((u >> 16) & 1u)) >> 16;   // RNE
    return (unsigned short)r;
}
__device__ __forceinline__ float bf2f(unsigned short u){
    return __uint_as_float(((unsigned int)u) << 16);
}

__device__ __forceinline__ EdgeData make_edge(const float* qpos, const float* ppos,
                                              int t, int s, float support, float sgn)
{
    float dx = sgn * (ppos[2*s]   - qpos[2*t])   / support;
    float dy = sgn * (ppos[2*s+1] - qpos[2*t+1]) / support;
    dx = fminf(1.f, fmaxf(-1.f, dx));
    dy = fminf(1.f, fmaxf(-1.f, dy));
    float r  = sqrtf(dx*dx + dy*dy + 1e-12f);
    float th = atan2f(dy, dx);
    float m0 = fminf(1.f, fmaxf(-1.f, 2.f*r - 1.f));
    float m1 = fminf(1.f, fmaxf(-1.f, th * 0.3183098861837907f));
    float u = (m0 + 1.f) * 3.5f;
    float v = (m1 + 1.f) * 3.5f;
    int ix = (int)u; if (ix > 6) ix = 6;
    int iy = (int)v; if (iy > 6) iy = 6;
    EdgeData ed;
    ed.src  = s;
    ed.ixiy = ix*8 + iy;
    ed.fx   = u - (float)ix;
    ed.fy   = v - (float)iy;
    return ed;
}

// ------- fused setup: edge prep (F+B) + partial hists + rowptrs + W prep ----
__global__ __launch_bounds__(256)
void setup_k(const float* __restrict__ fluid_pos, const float* __restrict__ bnd_pos,
             const int* __restrict__ f_tgt, const int* __restrict__ f_src, int nEf,
             const int* __restrict__ b_tgt, const int* __restrict__ b_src, int nEb,
             float support,
             EdgeData* __restrict__ edF, EdgeData* __restrict__ edB,
             int* __restrict__ hpart,              // [nA][64] per-block partial hist
             int* __restrict__ rowptrF, int* __restrict__ rowptrB,
             const float* __restrict__ Wc2, const float* __restrict__ Wc3,
             const float* __restrict__ Wc0,
             _Float16* __restrict__ wt2, _Float16* __restrict__ wt3,
             unsigned short* __restrict__ wb0,
             int nA, int nB, int nC)
{
    __shared__ int lc[64];
    __shared__ _Float16 T[64][98];
    int b = blockIdx.x, tid = threadIdx.x;
    if (b < nA){
        if (tid < 64) lc[tid] = 0;
        __syncthreads();
        int e = b*256 + tid;
        if (e < nEf){
            EdgeData d = make_edge(fluid_pos, fluid_pos, f_tgt[e], f_src[e], support, -1.f);
            edF[e] = d;
            atomicAdd(&lc[d.ixiy], 1);
        }
        __syncthreads();
        if (tid < 64) hpart[b*64 + tid] = lc[tid];   // plain store: no pre-zero needed
    } else if (b < nA + nB){
        int e = (b - nA)*256 + tid;
        if (e < nEb)
            edB[e] = make_edge(fluid_pos, bnd_pos, b_tgt[e], b_src[e], support, 1.f);
    } else if (b < nA + nB + nC){
        int t = (b - nA - nB)*256 + tid;
        if (t > NFL) return;
        if (t == NFL){ rowptrF[NFL] = nEf; return; }
        int lo = 0, hi = nEf;
        while (lo < hi){ int mid = (lo + hi) >> 1; if (f_tgt[mid] < t) lo = mid + 1; else hi = mid; }
        rowptrF[t] = lo;
    } else if (b < nA + nB + 2*nC){
        int t = (b - nA - nB - nC)*256 + tid;
        if (t > NFL) return;
        if (t == NFL){ rowptrB[NFL] = nEb; return; }
        int lo = 0, hi = nEb;
        while (lo < hi){ int mid = (lo + hi) >> 1; if (b_tgt[mid] < t) lo = mid + 1; else hi = mid; }
        rowptrB[t] = lo;
    } else {
        int wb = b - (nA + nB + 2*nC);     // 0..128
        if (wb < 64){
            const float* s = Wc2 + (size_t)wb * 96 * 64;
            for (int i = tid; i < 96*64; i += 256){ int k = i/64, c = i - k*64; T[c][k] = (_Float16)s[i]; }
            __syncthreads();
            _Float16* d = wt2 + (size_t)wb * 64 * 96;
            for (int i = tid; i < 96*64; i += 256){ int c = i/96, k = i - c*96; d[i] = T[c][k]; }
        } else if (wb < 128){
            int cell = wb - 64;
            const float* s = Wc3 + (size_t)cell * 64 * 64;
            for (int i = tid; i < 64*64; i += 256){ int k = i/64, c = i - k*64; T[c][k] = (_Float16)s[i]; }
            __syncthreads();
            _Float16* d = wt3 + (size_t)cell * 64 * 64;
            for (int i = tid; i < 64*64; i += 256){ int c = i/64, k = i - c*64; d[i] = T[c][k]; }
        } else {
            for (int i = tid; i < 64*8*32; i += 256) wb0[i] = f2bf(Wc0[i]);
        }
    }
}

// -- sum partial hists (16 waves, 4-way MLP) + scan + cursor init + pad fill -
__global__ __launch_bounds__(1024)
void scan_pad_k(const int* __restrict__ hpart, int nHB,
                int* __restrict__ cellOff,
                int* __restrict__ gcursor, int4* __restrict__ entries)
{
    __shared__ int red[16][64];
    __shared__ int cntS[64];
    __shared__ int offS[NCC+1];
    int tid = threadIdx.x;
    int c = tid & 63, j = tid >> 6;       // j in 0..15

    int s0 = 0, s1 = 0, s2 = 0, s3 = 0;
    int b = j;
    for (; b + 48 < nHB; b += 64){
        s0 += hpart[(b     )*64 + c];
        s1 += hpart[(b + 16)*64 + c];
        s2 += hpart[(b + 32)*64 + c];
        s3 += hpart[(b + 48)*64 + c];
    }
    for (; b < nHB; b += 16) s0 += hpart[b*64 + c];
    red[j][c] = s0 + s1 + s2 + s3;
    __syncthreads();

    if (tid < 64){
        int s = 0;
#pragma unroll
        for (int k = 0; k < 16; ++k) s += red[k][tid];
        cntS[tid] = s;
        gcursor[tid] = 0;
    }
    __syncthreads();
    if (tid == 0){
        int acc = 0;
        for (int k = 0; k < NCC; ++k){
            offS[k] = acc;
            acc += ((cntS[k] + PADQ - 1) / PADQ) * PADQ;
        }
        offS[NCC] = acc;
        for (int k = 0; k <= NCC; ++k) cellOff[k] = offS[k];
    }
    __syncthreads();
    for (int k = 0; k < NCC; ++k){
        int base = offS[k] + cntS[k];
        int pads = (offS[k+1] - offS[k]) - cntS[k];
        for (int i = tid; i < pads; i += 1024)
            entries[base + i] = make_int4(0, -1, 0, 0);
    }
}

__global__ void scatter_k(const EdgeData* __restrict__ ed, int nE,
                          const int* __restrict__ cellOff,
                          int* __restrict__ gcursor,
                          int4* __restrict__ entries)
{
    __shared__ int lc[64], base[64];
    int tid = threadIdx.x;
    if (tid < 64) lc[tid] = 0;
    __syncthreads();
    int e = blockIdx.x * blockDim.x + tid;
    bool ok = e < nE;
    EdgeData d; int k = 0, r = 0;
    if (ok){ d = ed[e]; k = d.ixiy; r = atomicAdd(&lc[k], 1); }
    __syncthreads();
    if (tid < 64 && lc[tid] > 0) base[tid] = atomicAdd(&gcursor[tid], lc[tid]);
    __syncthreads();
    if (ok){
        int slot = cellOff[k] + base[k] + r;
        entries[slot] = make_int4(d.src, e, __float_as_int(d.fx), __float_as_int(d.fy));
    }
}

// ---- MFMA cell-conv: 2 chunks/block, W in registers, LDS X-stage, LDS
// transpose tile for full-line msg writes. XCD-aware bijective block swizzle.
template<int CIN>
__global__ __launch_bounds__(256)
void conv_mfma_k(const _Float16* __restrict__ xh,        // [NFL][CIN]
                 const int4* __restrict__ entries,
                 const int* __restrict__ cellOff,
                 const _Float16* __restrict__ wt,        // [64][64][CIN] cout-major
                 _Float16* __restrict__ msg)             // [edge][64]
{
    constexpr int COUT = 64;
    constexpr int XROW = CIN*2 + 16;       // bytes: 208 (96) / 144 (64)
    constexpr int C16  = CIN*2/16;
    constexpr int NK   = CIN/32;
    constexpr int NCH  = PADQ/64;          // 2

    __shared__ unsigned char XL[64 * XROW];
    __shared__ _Float16 MT[64][68];        // 64 couts + 4 pad (8.7 KB)
    __shared__ float BW[4][64];
    __shared__ int   SRC[64];
    __shared__ int   EID[64];

    int total = cellOff[NCC];              // multiple of PADQ
    // bijective XCD-aware swizzle (m204)
    int nwg = gridDim.x, bid = blockIdx.x;
    int q = nwg >> 3, r = nwg & 7;
    int xcd = bid & 7, idx = bid >> 3;
    int swz = (xcd < r ? xcd*(q+1) : r*(q+1) + (xcd - r)*q) + idx;
    int pb = swz * PADQ;
    if (pb >= total) return;
    int tid = threadIdx.x;

    int lo_ = 0, hi_ = NCC;
    while (hi_ - lo_ > 1){ int mid = (lo_ + hi_) >> 1; if (cellOff[mid] <= pb) lo_ = mid; else hi_ = mid; }
    const int cell = lo_;
    const int kc[4] = { cell, cell+1, cell+8, cell+9 };

    const int lane = tid & 63, wv = tid >> 6;
    const int lr = lane & 15, lg = lane >> 4;
    const int cb = wv * 16;

    // hoist this wave's W slice into registers (48 VGPR @96 / 32 @64)
    const _Float16* wbase = wt + (size_t)(cb + lr) * CIN + lg * 8;
    half8 bfr[4][NK];
#pragma unroll
    for (int cr = 0; cr < 4; ++cr)
#pragma unroll
        for (int kk = 0; kk < NK; ++kk)
            bfr[cr][kk] = *(const half8*)(wbase + (size_t)kc[cr]*(COUT*CIN) + kk*32);

    for (int ch = 0; ch < NCH; ++ch){
        int p0 = pb + ch * 64;

        if (tid < 64){
            int4 en = entries[p0 + tid];
            bool ok = en.y >= 0;
            float fx = __int_as_float(en.z), fy = __int_as_float(en.w);
            BW[0][tid] = ok ? (1.f-fx)*(1.f-fy) : 0.f;
            BW[1][tid] = ok ? (1.f-fx)*fy       : 0.f;
            BW[2][tid] = ok ? fx*(1.f-fy)       : 0.f;
            BW[3][tid] = ok ? fx*fy             : 0.f;
            SRC[tid] = en.x;
            EID[tid] = en.y;
        }
        __syncthreads();
        for (int i = tid; i < 64*C16; i += 256){
            int e = i / C16, c = i - e*C16;
            const uint4* sp = (const uint4*)(xh + (size_t)SRC[e]*CIN) + c;
            *(uint4*)(&XL[e*XROW + 16*c]) = *sp;
        }
        __syncthreads();

        f32x4 acc[4][4];   // [corner][edge-group]
#pragma unroll
        for (int cr = 0; cr < 4; ++cr)
#pragma unroll
            for (int ae = 0; ae < 4; ++ae)
                acc[cr][ae] = (f32x4)0.f;

#pragma unroll
        for (int kk = 0; kk < NK; ++kk){
            half8 a[4];
#pragma unroll
            for (int ae = 0; ae < 4; ++ae)
                a[ae] = *(const half8*)(&XL[(16*ae + lr)*XROW + kk*64 + lg*16]);
#pragma unroll
            for (int cr = 0; cr < 4; ++cr)
#pragma unroll
                for (int ae = 0; ae < 4; ++ae)
                    acc[cr][ae] = __builtin_amdgcn_mfma_f32_16x16x32_f16(a[ae], bfr[cr][kk], acc[cr][ae], 0, 0, 0);
        }

        // bilinear combine -> LDS transpose tile
#pragma unroll
        for (int ae = 0; ae < 4; ++ae){
#pragma unroll
            for (int r2 = 0; r2 < 4; ++r2){
                int E = 16*ae + lg*4 + r2;
                float v = BW[0][E]*acc[0][ae][r2] + BW[1][E]*acc[1][ae][r2]
                        + BW[2][E]*acc[2][ae][r2] + BW[3][E]*acc[3][ae][r2];
                MT[E][cb + lr] = (_Float16)v;
            }
        }
        __syncthreads();

        // coalesced per-edge row write: 8 threads x 16B = 128B contiguous
#pragma unroll
        for (int p = 0; p < 2; ++p){
            int f = tid + p*256;           // 0..511
            int e = f >> 3, j = f & 7;
            int eid = EID[e];
            if (eid >= 0)
                *(uint4*)(msg + (size_t)eid*COUT + j*8) = *(const uint4*)(&MT[e][j*8]);
        }
        __syncthreads();   // protect MT/BW/SRC/EID/XL before next chunk
    }
}

// --------------------------- final conv (64->2): thread-per-edge, fp16 x rows
__global__ __launch_bounds__(128)
void conv2_msg_k(const _Float16* __restrict__ xh,        // relu(y2) fp16 [NFL][64]
                 const int4* __restrict__ entries,
                 const int* __restrict__ cellOff,
                 const float* __restrict__ Wc,
                 float* __restrict__ msg2)                // [edge][2]
{
    __shared__ float WLf[4][64][2];
    int total = cellOff[NCC];
    int p0 = blockIdx.x * 128;
    if (p0 >= total) return;
    int tid = threadIdx.x;

    int lo = 0, hi = NCC;
    while (hi - lo > 1){ int mid = (lo + hi) >> 1; if (cellOff[mid] <= p0) lo = mid; else hi = mid; }
    const int cell = lo;
    const int kc[4] = { cell, cell + 1, cell + 8, cell + 9 };
#pragma unroll
    for (int c = 0; c < 4; ++c)
        ((float*)&WLf[c][0][0])[tid] = Wc[(size_t)kc[c] * 128 + tid];
    __syncthreads();

    int4 en = entries[p0 + tid];
    if (en.y < 0) return;
    float fx = __int_as_float(en.z), fy = __int_as_float(en.w);
    const _Float16* xp = xh + (size_t)en.x * 64;

    float a[4][2] = {{0.f,0.f},{0.f,0.f},{0.f,0.f},{0.f,0.f}};
#pragma unroll
    for (int ci = 0; ci < 64; ci += 8){
        half8 v = *(const half8*)(xp + ci);
#pragma unroll
        for (int j = 0; j < 8; ++j){
            float xe = (float)v[j];
#pragma unroll
            for (int cr = 0; cr < 4; ++cr){
                a[cr][0] += xe * WLf[cr][ci+j][0];
                a[cr][1] += xe * WLf[cr][ci+j][1];
            }
        }
    }
    float w0 = (1.f-fx)*(1.f-fy), w1 = (1.f-fx)*fy, w2 = fx*(1.f-fy), w3 = fx*fy;
    float m0 = w0*a[0][0] + w1*a[1][0] + w2*a[2][0] + w3*a[3][0];
    float m1 = w0*a[0][1] + w1*a[1][1] + w2*a[2][1] + w3*a[3][1];
    *(float2*)(msg2 + (size_t)en.y * 2) = make_float2(m0, m1);
}

// --------------------------- final combine: thread-per-target, out = .../128
__global__ __launch_bounds__(256)
void final_combine_k(const _Float16* __restrict__ xh,    // relu(y2) fp16 [NFL][64]
                     const float* __restrict__ Wl3, const float* __restrict__ bl3,
                     const float* __restrict__ bc4,
                     const float* __restrict__ msg2,
                     const int* __restrict__ rowptr,
                     float* __restrict__ out)
{
    __shared__ float WS[128];
    int tid = threadIdx.x;
    if (tid < 128) WS[tid] = Wl3[tid];
    __syncthreads();

    int t = blockIdx.x * blockDim.x + tid;
    if (t >= NFL) return;
    int eb = rowptr[t], ee = rowptr[t+1];

    float a0 = bc4[0] + bl3[0];
    float a1 = bc4[1] + bl3[1];
    const _Float16* pr = xh + (size_t)t * 64;
#pragma unroll
    for (int ci = 0; ci < 64; ci += 8){
        half8 v = *(const half8*)(pr + ci);
#pragma unroll
        for (int j = 0; j < 8; ++j){
            float xe = (float)v[j];
            a0 += xe * WS[(ci+j)*2];
            a1 += xe * WS[(ci+j)*2 + 1];
        }
    }
    for (int e = eb; e < ee; ++e){
        float2 m = *(const float2*)(msg2 + (size_t)e * 2);
        a0 += m.x; a1 += m.y;
    }
    out[(size_t)t*2]     = a0 * (1.0f/128.0f);
    out[(size_t)t*2 + 1] = a1 * (1.0f/128.0f);
}

// ---- combine0: lin + DIRECT conv0 (Wc0 in LDS) + fused bconv; ansA + xbA ---
__global__ __launch_bounds__(256)
void combine0_k(const float* __restrict__ feat,
                const float* __restrict__ bnd_feat,
                const float* __restrict__ Wl0, const float* __restrict__ bl0,
                const float* __restrict__ bc0,
                const float* __restrict__ Wc1, const float* __restrict__ bc1,
                const EdgeData* __restrict__ edB,
                const int* __restrict__ rowptrB,
                const EdgeData* __restrict__ edF,
                const int* __restrict__ rowptrF,
                const unsigned short* __restrict__ wb0,  // [64][8][32] bf16
                float* __restrict__ ansA,
                _Float16* __restrict__ xbA)              // [NFL][96] relu fp16
{
    __shared__ unsigned short WL0[64*8*32];              // 32 KB
    int tid = threadIdx.x;
    for (int i = tid; i < 64*8*32/8; i += 256)
        ((uint4*)WL0)[i] = ((const uint4*)wb0)[i];
    __syncthreads();

    int t = blockIdx.x * 4 + (tid >> 6);
    if (t >= NFL) return;
    int lane = tid & 63;

    if (lane < 32){
        // lin (col = lane)
        float a = bl0[lane];
#pragma unroll
        for (int ci = 0; ci < 8; ++ci)
            a += feat[t*8 + ci] * Wl0[ci*32 + lane];
        ansA[(size_t)t*96 + lane] = a;
        xbA[(size_t)t*96 + lane]  = (_Float16)frelu(a);

        // bconv (col = 64 + lane), W from global (tiny edge count)
        float b = bc1[lane];
        int eb = rowptrB[t], ee = rowptrB[t+1];
        for (int e = eb; e < ee; ++e){
            EdgeData d = edB[e];
            const float* xp = bnd_feat + (size_t)d.src * 8;
            const float* wp = Wc1 + (size_t)d.ixiy * 256 + lane;
            float t00 = 0.f, t01 = 0.f, t10 = 0.f, t11 = 0.f;
#pragma unroll
            for (int ci = 0; ci < 8; ++ci){
                float xv = xp[ci];
                t00 += xv * wp[ci*32];
                t01 += xv * wp[ci*32 + 256];
                t10 += xv * wp[ci*32 + 2048];
                t11 += xv * wp[ci*32 + 2304];
            }
            float wx1 = d.fx, wy1 = d.fy;
            float wx0 = 1.f - wx1, wy0 = 1.f - wy1;
            b += (wx0*wy0)*t00 + (wx0*wy1)*t01 + (wx1*wy0)*t10 + (wx1*wy1)*t11;
        }
        ansA[(size_t)t*96 + 64 + lane] = b;
        xbA[(size_t)t*96 + 64 + lane]  = (_Float16)frelu(b);
    } else {
        // conv0 direct (col = 32 + c), W from LDS (bf16)
        int c = lane - 32;
        float a = bc0[c];
        int eb = rowptrF[t], ee = rowptrF[t+1];
        for (int e = eb; e < ee; ++e){
            EdgeData d = edF[e];
            const float* xp = feat + (size_t)d.src * 8;
            const unsigned short* wp = WL0 + d.ixiy * 256 + c;
            float t00 = 0.f, t01 = 0.f, t10 = 0.f, t11 = 0.f;
#pragma unroll
            for (int ci = 0; ci < 8; ++ci){
                float xv = xp[ci];
                t00 += xv * bf2f(wp[ci*32]);
                t01 += xv * bf2f(wp[ci*32 + 256]);
                t10 += xv * bf2f(wp[ci*32 + 2048]);
                t11 += xv * bf2f(wp[ci*32 + 2304]);
            }
            float wx1 = d.fx, wy1 = d.fy;
            float wx0 = 1.f - wx1, wy0 = 1.f - wy1;
            a += (wx0*wy0)*t00 + (wx0*wy1)*t01 + (wx1*wy0)*t10 + (wx1*wy1)*t11;
        }
        ansA[(size_t)t*96 + 32 + c] = a;
        xbA[(size_t)t*96 + 32 + c]  = (_Float16)frelu(a);
    }
}

// ------- combine: msg-sum + dns (fp16 input) + bias (+resid); y + relu fp16
template<int CIN, bool RESID, bool WRITE_XB>
__global__ __launch_bounds__(256)
void combine12_k(const float* __restrict__ yprev,        // for residual only
                 const _Float16* __restrict__ xprev,     // relu'd fp16 [NFL][CIN]
                 const float* __restrict__ Wl, const float* __restrict__ bl,
                 const float* __restrict__ bc,
                 const _Float16* __restrict__ msg,       // [edge][64]
                 const int* __restrict__ rowptr,
                 float* __restrict__ y,
                 _Float16* __restrict__ xbnext)          // [NFL][64]
{
    int t = blockIdx.x * (blockDim.x >> 6) + (threadIdx.x >> 6);
    if (t >= NFL) return;
    int lane = threadIdx.x & 63;
    int eb = rowptr[t], ee = rowptr[t+1];

    const _Float16* pr = xprev + (size_t)t * CIN;
    float acc = bc[lane] + bl[lane];
#pragma unroll 8
    for (int ci = 0; ci < CIN; ++ci)
        acc += (float)pr[ci] * Wl[ci*64 + lane];
    if (RESID) acc += yprev[(size_t)t*64 + lane];

    for (int e = eb; e < ee; ++e)
        acc += (float)msg[(size_t)e*64 + lane];
    y[(size_t)t*64 + lane] = acc;

    if (WRITE_XB)
        xbnext[(size_t)t*64 + lane] = (_Float16)frelu(acc);
}

// ---------------------------------------------------------------------------
extern "C" void kernel_launch(void* const* d_in, const int* in_sizes, int n_in,
                              void* d_out, int out_size, void* d_ws, size_t ws_size,
                              hipStream_t stream)
{
    const float* fluid_pos  = (const float*)d_in[0];
    const float* bnd_pos    = (const float*)d_in[1];
    const float* fluid_feat = (const float*)d_in[2];
    const float* bnd_feat   = (const float*)d_in[3];
    const int*   f_tgt      = (const int*)  d_in[4];
    const int*   f_src      = (const int*)  d_in[5];
    const int*   b_tgt      = (const int*)  d_in[6];
    const int*   b_src      = (const int*)  d_in[7];
    const float* Wc0 = (const float*)d_in[8];  const float* bc0 = (const float*)d_in[9];
    const float* Wc1 = (const float*)d_in[10]; const float* bc1 = (const float*)d_in[11];
    const float* Wc2 = (const float*)d_in[12]; const float* bc2 = (const float*)d_in[13];
    const float* Wc3 = (const float*)d_in[14]; const float* bc3 = (const float*)d_in[15];
    const float* Wc4 = (const float*)d_in[16]; const float* bc4 = (const float*)d_in[17];
    const float* Wl0 = (const float*)d_in[18]; const float* bl0 = (const float*)d_in[19];
    const float* Wl1 = (const float*)d_in[20]; const float* bl1 = (const float*)d_in[21];
    const float* Wl2 = (const float*)d_in[22]; const float* bl2 = (const float*)d_in[23];
    const float* Wl3 = (const float*)d_in[24]; const float* bl3 = (const float*)d_in[25];

    int nEf = in_sizes[4];
    int nEb = in_sizes[6];
    int entPadMax = nEf + NCC * PADQ;
    float support = (float)sqrt(16.0 / (M_PI * 16384.0));

    int nA = (nEf + 255)/256, nB = (nEb + 255)/256, nC = (NFL + 256)/256;

    char* w = (char*)d_ws;
    auto alloc = [&](size_t bytes){ char* r = w; w += (bytes + 255) & ~(size_t)255; return r; };
    EdgeData* edF      = (EdgeData*)alloc((size_t)nEf * sizeof(EdgeData));
    EdgeData* edB      = (EdgeData*)alloc((size_t)nEb * sizeof(EdgeData));
    int*      hpart    = (int*)     alloc((size_t)nA * 64 * sizeof(int));
    int*      cellOff  = (int*)     alloc(64 * sizeof(int));
    int*      gcursor  = (int*)     alloc(64 * sizeof(int));
    int*      rowptrF  = (int*)     alloc((NFL+1) * sizeof(int));
    int*      rowptrB  = (int*)     alloc((NFL+1) * sizeof(int));
    int4*     entries  = (int4*)    alloc((size_t)entPadMax * sizeof(int4));
    unsigned short* wb0 = (unsigned short*)alloc((size_t)64*8*32 * 2);
    _Float16* wt2      = (_Float16*)alloc((size_t)64*64*96 * 2);  // [cell][cout][k]
    _Float16* wt3      = (_Float16*)alloc((size_t)64*64*64 * 2);
    _Float16* xbA      = (_Float16*)alloc((size_t)NFL*96 * 2);
    _Float16* xb1      = (_Float16*)alloc((size_t)NFL*64 * 2);
    _Float16* xb2      = (_Float16*)alloc((size_t)NFL*64 * 2);
    float*    ansA     = (float*)   alloc((size_t)NFL * 96 * sizeof(float));
    float*    y1       = (float*)   alloc((size_t)NFL * 64 * sizeof(float));
    float*    y2       = (float*)   alloc((size_t)NFL * 64 * sizeof(float));
    _Float16* msg      = (_Float16*)alloc((size_t)nEf * 64 * 2);
    float*    msg2     = (float*)   alloc((size_t)nEf * 2 * sizeof(float));

    // ---- setup: fused prep (edges F/B, partial hists, rowptrs, W-prep)
    setup_k<<<nA + nB + 2*nC + 129, 256, 0, stream>>>(fluid_pos, bnd_pos,
                                                      f_tgt, f_src, nEf,
                                                      b_tgt, b_src, nEb, support,
                                                      edF, edB, hpart, rowptrF, rowptrB,
                                                      Wc2, Wc3, Wc0, wt2, wt3, wb0,
                                                      nA, nB, nC);
    scan_pad_k<<<1, 1024, 0, stream>>>(hpart, nA, cellOff, gcursor, entries);
    scatter_k<<<nA, 256, 0, stream>>>(edF, nEf, cellOff, gcursor, entries);

    int gridM = (entPadMax + PADQ - 1) / PADQ;
    int gridC = (entPadMax + 127) / 128;
    dim3 tgrid(NFL/4);

    // ---- input block: conv0 fused INTO combine0 (Wc0 staged in LDS)
    combine0_k<<<tgrid, 256, 0, stream>>>(fluid_feat, bnd_feat, Wl0, bl0, bc0,
                                          Wc1, bc1, edB, rowptrB,
                                          edF, rowptrF, wb0, ansA, xbA);

    // ---- block 1
    conv_mfma_k<96><<<gridM, 256, 0, stream>>>(xbA, entries, cellOff, wt2, msg);
    combine12_k<96,false,true><<<tgrid, 256, 0, stream>>>(nullptr, xbA, Wl1, bl1, bc2, msg, rowptrF, y1, xb1);

    // ---- block 2
    conv_mfma_k<64><<<gridM, 256, 0, stream>>>(xb1, entries, cellOff, wt3, msg);
    combine12_k<64,true,true><<<tgrid, 256, 0, stream>>>(y1, xb1, Wl2, bl2, bc3, msg, rowptrF, y2, xb2);

    // ---- block 3 (final): thread-per-edge conv + thread-per-target combine
    conv2_msg_k<<<gridC, 128, 0, stream>>>(xb2, entries, cellOff, Wc4, msg2);
    final_combine_k<<<(NFL+255)/256, 256, 0, stream>>>(xb2, Wl3, bl3, bc4, msg2, rowptrF, (float*)d_out);
}

// Round 18
// 246.937 us; speedup vs baseline: 1.0661x; 1.0661x over previous
//
#include <hip/hip_runtime.h>
#include <math.h>
#include <stdint.h>

#define NFL   16384
#define NCC   55      // base cells: ix,iy in 0..6 -> ixiy = ix*8+iy in 0..54
#define PADQ  128     // bucket pad quantum (=2 conv chunks per block)

struct EdgeData { int src; int ixiy; float fx; float fy; };

typedef _Float16 half8 __attribute__((ext_vector_type(8)));
typedef __attribute__((ext_vector_type(4))) float f32x4;

__device__ __forceinline__ float frelu(float x){ return x > 0.f ? x : 0.f; }
__device__ __forceinline__ unsigned short f2bf(float f){
    unsigned int u = __float_as_uint(f);
    unsigned int r = (u + 0x7FFFu + ((u >> 16) & 1u)) >> 16;   // RNE
    return (unsigned short)r;
}

__device__ __forceinline__ EdgeData make_edge(const float* qpos, const float* ppos,
                                              int t, int s, float support, float sgn)
{
    float dx = sgn * (ppos[2*s]   - qpos[2*t])   / support;
    float dy = sgn * (ppos[2*s+1] - qpos[2*t+1]) / support;
    dx = fminf(1.f, fmaxf(-1.f, dx));
    dy = fminf(1.f, fmaxf(-1.f, dy));
    float r  = sqrtf(dx*dx + dy*dy + 1e-12f);
    float th = atan2f(dy, dx);
    float m0 = fminf(1.f, fmaxf(-1.f, 2.f*r - 1.f));
    float m1 = fminf(1.f, fmaxf(-1.f, th * 0.3183098861837907f));
    float u = (m0 + 1.f) * 3.5f;
    float v = (m1 + 1.f) * 3.5f;
    int ix = (int)u; if (ix > 6) ix = 6;
    int iy = (int)v; if (iy > 6) iy = 6;
    EdgeData ed;
    ed.src  = s;
    ed.ixiy = ix*8 + iy;
    ed.fx   = u - (float)ix;
    ed.fy   = v - (float)iy;
    return ed;
}

// ------- fused setup: edge prep (F+B) + partial hists + rowptrs + W prep ----
__global__ __launch_bounds__(256)
void setup_k(const float* __restrict__ fluid_pos, const float* __restrict__ bnd_pos,
             const int* __restrict__ f_tgt, const int* __restrict__ f_src, int nEf,
             const int* __restrict__ b_tgt, const int* __restrict__ b_src, int nEb,
             float support,
             EdgeData* __restrict__ edF, EdgeData* __restrict__ edB,
             int* __restrict__ hpart,              // [nA][64] per-block partial hist
             int* __restrict__ rowptrF, int* __restrict__ rowptrB,
             const float* __restrict__ Wc2, const float* __restrict__ Wc3,
             const float* __restrict__ Wc0,
             _Float16* __restrict__ wt2, _Float16* __restrict__ wt3,
             unsigned short* __restrict__ wb0,
             int nA, int nB, int nC)
{
    __shared__ int lc[64];
    __shared__ _Float16 T[64][98];
    int b = blockIdx.x, tid = threadIdx.x;
    if (b < nA){
        if (tid < 64) lc[tid] = 0;
        __syncthreads();
        int e = b*256 + tid;
        if (e < nEf){
            EdgeData d = make_edge(fluid_pos, fluid_pos, f_tgt[e], f_src[e], support, -1.f);
            edF[e] = d;
            atomicAdd(&lc[d.ixiy], 1);
        }
        __syncthreads();
        if (tid < 64) hpart[b*64 + tid] = lc[tid];   // plain store: no pre-zero needed
    } else if (b < nA + nB){
        int e = (b - nA)*256 + tid;
        if (e < nEb)
            edB[e] = make_edge(fluid_pos, bnd_pos, b_tgt[e], b_src[e], support, 1.f);
    } else if (b < nA + nB + nC){
        int t = (b - nA - nB)*256 + tid;
        if (t > NFL) return;
        if (t == NFL){ rowptrF[NFL] = nEf; return; }
        int lo = 0, hi = nEf;
        while (lo < hi){ int mid = (lo + hi) >> 1; if (f_tgt[mid] < t) lo = mid + 1; else hi = mid; }
        rowptrF[t] = lo;
    } else if (b < nA + nB + 2*nC){
        int t = (b - nA - nB - nC)*256 + tid;
        if (t > NFL) return;
        if (t == NFL){ rowptrB[NFL] = nEb; return; }
        int lo = 0, hi = nEb;
        while (lo < hi){ int mid = (lo + hi) >> 1; if (b_tgt[mid] < t) lo = mid + 1; else hi = mid; }
        rowptrB[t] = lo;
    } else {
        int wb = b - (nA + nB + 2*nC);     // 0..128
        if (wb < 64){
            const float* s = Wc2 + (size_t)wb * 96 * 64;
            for (int i = tid; i < 96*64; i += 256){ int k = i/64, c = i - k*64; T[c][k] = (_Float16)s[i]; }
            __syncthreads();
            _Float16* d = wt2 + (size_t)wb * 64 * 96;
            for (int i = tid; i < 96*64; i += 256){ int c = i/96, k = i - c*96; d[i] = T[c][k]; }
        } else if (wb < 128){
            int cell = wb - 64;
            const float* s = Wc3 + (size_t)cell * 64 * 64;
            for (int i = tid; i < 64*64; i += 256){ int k = i/64, c = i - k*64; T[c][k] = (_Float16)s[i]; }
            __syncthreads();
            _Float16* d = wt3 + (size_t)cell * 64 * 64;
            for (int i = tid; i < 64*64; i += 256){ int c = i/64, k = i - c*64; d[i] = T[c][k]; }
        } else {
            for (int i = tid; i < 64*8*32; i += 256) wb0[i] = f2bf(Wc0[i]);
        }
    }
}

// -- sum partial hists (16 waves, 4-way MLP) + scan + cursor init + pad fill -
__global__ __launch_bounds__(1024)
void scan_pad_k(const int* __restrict__ hpart, int nHB,
                int* __restrict__ cellOff,
                int* __restrict__ gcursor, int4* __restrict__ entries)
{
    __shared__ int red[16][64];
    __shared__ int cntS[64];
    __shared__ int offS[NCC+1];
    int tid = threadIdx.x;
    int c = tid & 63, j = tid >> 6;       // j in 0..15

    int s0 = 0, s1 = 0, s2 = 0, s3 = 0;
    int b = j;
    for (; b + 48 < nHB; b += 64){
        s0 += hpart[(b     )*64 + c];
        s1 += hpart[(b + 16)*64 + c];
        s2 += hpart[(b + 32)*64 + c];
        s3 += hpart[(b + 48)*64 + c];
    }
    for (; b < nHB; b += 16) s0 += hpart[b*64 + c];
    red[j][c] = s0 + s1 + s2 + s3;
    __syncthreads();

    if (tid < 64){
        int s = 0;
#pragma unroll
        for (int k = 0; k < 16; ++k) s += red[k][tid];
        cntS[tid] = s;
        gcursor[tid] = 0;
    }
    __syncthreads();
    if (tid == 0){
        int acc = 0;
        for (int k = 0; k < NCC; ++k){
            offS[k] = acc;
            acc += ((cntS[k] + PADQ - 1) / PADQ) * PADQ;
        }
        offS[NCC] = acc;
        for (int k = 0; k <= NCC; ++k) cellOff[k] = offS[k];
    }
    __syncthreads();
    for (int k = 0; k < NCC; ++k){
        int base = offS[k] + cntS[k];
        int pads = (offS[k+1] - offS[k]) - cntS[k];
        for (int i = tid; i < pads; i += 1024)
            entries[base + i] = make_int4(0, -1, 0, 0);
    }
}

__global__ void scatter_k(const EdgeData* __restrict__ ed, int nE,
                          const int* __restrict__ cellOff,
                          int* __restrict__ gcursor,
                          int4* __restrict__ entries)
{
    __shared__ int lc[64], base[64];
    int tid = threadIdx.x;
    if (tid < 64) lc[tid] = 0;
    __syncthreads();
    int e = blockIdx.x * blockDim.x + tid;
    bool ok = e < nE;
    EdgeData d; int k = 0, r = 0;
    if (ok){ d = ed[e]; k = d.ixiy; r = atomicAdd(&lc[k], 1); }
    __syncthreads();
    if (tid < 64 && lc[tid] > 0) base[tid] = atomicAdd(&gcursor[tid], lc[tid]);
    __syncthreads();
    if (ok){
        int slot = cellOff[k] + base[k] + r;
        entries[slot] = make_int4(d.src, e, __float_as_int(d.fx), __float_as_int(d.fy));
    }
}

// ---- MFMA cell-conv: 2 chunks/block, W in registers, LDS X-stage, LDS
// transpose tile for full-line msg writes. XCD-aware bijective block swizzle.
template<int CIN>
__global__ __launch_bounds__(256)
void conv_mfma_k(const _Float16* __restrict__ xh,        // [NFL][CIN]
                 const int4* __restrict__ entries,
                 const int* __restrict__ cellOff,
                 const _Float16* __restrict__ wt,        // [64][64][CIN] cout-major
                 _Float16* __restrict__ msg)             // [edge][64]
{
    constexpr int COUT = 64;
    constexpr int XROW = CIN*2 + 16;       // bytes: 208 (96) / 144 (64)
    constexpr int C16  = CIN*2/16;
    constexpr int NK   = CIN/32;
    constexpr int NCH  = PADQ/64;          // 2

    __shared__ unsigned char XL[64 * XROW];
    __shared__ _Float16 MT[64][68];        // 64 couts + 4 pad (8.7 KB)
    __shared__ float BW[4][64];
    __shared__ int   SRC[64];
    __shared__ int   EID[64];

    int total = cellOff[NCC];              // multiple of PADQ
    // bijective XCD-aware swizzle (m204)
    int nwg = gridDim.x, bid = blockIdx.x;
    int q = nwg >> 3, r = nwg & 7;
    int xcd = bid & 7, idx = bid >> 3;
    int swz = (xcd < r ? xcd*(q+1) : r*(q+1) + (xcd - r)*q) + idx;
    int pb = swz * PADQ;
    if (pb >= total) return;
    int tid = threadIdx.x;

    int lo_ = 0, hi_ = NCC;
    while (hi_ - lo_ > 1){ int mid = (lo_ + hi_) >> 1; if (cellOff[mid] <= pb) lo_ = mid; else hi_ = mid; }
    const int cell = lo_;
    const int kc[4] = { cell, cell+1, cell+8, cell+9 };

    const int lane = tid & 63, wv = tid >> 6;
    const int lr = lane & 15, lg = lane >> 4;
    const int cb = wv * 16;

    // hoist this wave's W slice into registers (48 VGPR @96 / 32 @64)
    const _Float16* wbase = wt + (size_t)(cb + lr) * CIN + lg * 8;
    half8 bfr[4][NK];
#pragma unroll
    for (int cr = 0; cr < 4; ++cr)
#pragma unroll
        for (int kk = 0; kk < NK; ++kk)
            bfr[cr][kk] = *(const half8*)(wbase + (size_t)kc[cr]*(COUT*CIN) + kk*32);

    for (int ch = 0; ch < NCH; ++ch){
        int p0 = pb + ch * 64;

        if (tid < 64){
            int4 en = entries[p0 + tid];
            bool ok = en.y >= 0;
            float fx = __int_as_float(en.z), fy = __int_as_float(en.w);
            BW[0][tid] = ok ? (1.f-fx)*(1.f-fy) : 0.f;
            BW[1][tid] = ok ? (1.f-fx)*fy       : 0.f;
            BW[2][tid] = ok ? fx*(1.f-fy)       : 0.f;
            BW[3][tid] = ok ? fx*fy             : 0.f;
            SRC[tid] = en.x;
            EID[tid] = en.y;
        }
        __syncthreads();
        for (int i = tid; i < 64*C16; i += 256){
            int e = i / C16, c = i - e*C16;
            const uint4* sp = (const uint4*)(xh + (size_t)SRC[e]*CIN) + c;
            *(uint4*)(&XL[e*XROW + 16*c]) = *sp;
        }
        __syncthreads();

        f32x4 acc[4][4];   // [corner][edge-group]
#pragma unroll
        for (int cr = 0; cr < 4; ++cr)
#pragma unroll
            for (int ae = 0; ae < 4; ++ae)
                acc[cr][ae] = (f32x4)0.f;

#pragma unroll
        for (int kk = 0; kk < NK; ++kk){
            half8 a[4];
#pragma unroll
            for (int ae = 0; ae < 4; ++ae)
                a[ae] = *(const half8*)(&XL[(16*ae + lr)*XROW + kk*64 + lg*16]);
#pragma unroll
            for (int cr = 0; cr < 4; ++cr)
#pragma unroll
                for (int ae = 0; ae < 4; ++ae)
                    acc[cr][ae] = __builtin_amdgcn_mfma_f32_16x16x32_f16(a[ae], bfr[cr][kk], acc[cr][ae], 0, 0, 0);
        }

        // bilinear combine -> LDS transpose tile
#pragma unroll
        for (int ae = 0; ae < 4; ++ae){
#pragma unroll
            for (int r2 = 0; r2 < 4; ++r2){
                int E = 16*ae + lg*4 + r2;
                float v = BW[0][E]*acc[0][ae][r2] + BW[1][E]*acc[1][ae][r2]
                        + BW[2][E]*acc[2][ae][r2] + BW[3][E]*acc[3][ae][r2];
                MT[E][cb + lr] = (_Float16)v;
            }
        }
        __syncthreads();

        // coalesced per-edge row write: 8 threads x 16B = 128B contiguous
#pragma unroll
        for (int p = 0; p < 2; ++p){
            int f = tid + p*256;           // 0..511
            int e = f >> 3, j = f & 7;
            int eid = EID[e];
            if (eid >= 0)
                *(uint4*)(msg + (size_t)eid*COUT + j*8) = *(const uint4*)(&MT[e][j*8]);
        }
        __syncthreads();   // protect MT/BW/SRC/EID/XL before next chunk
    }
}

// -------------------------- fp32 cell-conv (conv0: CIN=8, COUT=32), fp16 msg
template<int CIN, int COUT, int TILE_E, bool RELU>
__global__ __launch_bounds__(128)
void conv_cell_k(const float* __restrict__ x,
                 const int4* __restrict__ entries,
                 const int* __restrict__ cellOff,
                 const unsigned short* __restrict__ Wbf,
                 _Float16* __restrict__ msg)             // [edge][COUT]
{
    constexpr int TEP = TILE_E + 4;
    constexpr int EG  = TILE_E / 4;
    constexpr int CG  = COUT / 8;
    static_assert(EG * CG == 128, "tile/thread mismatch");
    constexpr int C4  = CIN / 4;

    __shared__ float XT[CIN][TEP];
    __shared__ unsigned short WLc[4][CIN][COUT];
    __shared__ int4 EN[TILE_E];

    int total = cellOff[NCC];
    int p0 = blockIdx.x * TILE_E;
    if (p0 >= total) return;
    int tid = threadIdx.x;

    int lo = 0, hi = NCC;
    while (hi - lo > 1){ int mid = (lo + hi) >> 1; if (cellOff[mid] <= p0) lo = mid; else hi = mid; }
    const int cell = lo;

    for (int i = tid; i < TILE_E; i += 128) EN[i] = entries[p0 + i];

    const int kc[4] = { cell, cell + 1, cell + 8, cell + 9 };
#pragma unroll
    for (int c = 0; c < 4; ++c){
        const uint4* s = (const uint4*)(Wbf + (size_t)kc[c] * (CIN * COUT));
        uint4* dlds = (uint4*)(&WLc[c][0][0]);
        for (int i = tid; i < CIN * COUT / 8; i += 128) dlds[i] = s[i];
    }
    __syncthreads();

    for (int i = tid; i < TILE_E * C4; i += 128){
        int e  = i / C4;
        int c4 = i - e * C4;
        int4 en = EN[e];
        float4 v = make_float4(0.f, 0.f, 0.f, 0.f);
        if (en.y >= 0){
            v = *(const float4*)(x + (size_t)en.x * CIN + 4 * c4);
            if (RELU){ v.x = frelu(v.x); v.y = frelu(v.y); v.z = frelu(v.z); v.w = frelu(v.w); }
        }
        XT[4*c4+0][e] = v.x;
        XT[4*c4+1][e] = v.y;
        XT[4*c4+2][e] = v.z;
        XT[4*c4+3][e] = v.w;
    }
    __syncthreads();

    const int egrp = tid % EG;
    const int cgrp = tid / EG;
    const int e0 = egrp * 4;

    float fx[4], fy[4];
    int eid[4];
#pragma unroll
    for (int j = 0; j < 4; ++j){
        int4 en = EN[e0 + j];
        fx[j] = __int_as_float(en.z);
        fy[j] = __int_as_float(en.w);
        eid[j] = en.y;
    }

    float accT[4][8];
#pragma unroll
    for (int j = 0; j < 4; ++j)
#pragma unroll
        for (int c = 0; c < 8; ++c) accT[j][c] = 0.f;

#pragma unroll
    for (int cr = 0; cr < 4; ++cr){
        float accC[4][8];
#pragma unroll
        for (int j = 0; j < 4; ++j)
#pragma unroll
            for (int c = 0; c < 8; ++c) accC[j][c] = 0.f;

#pragma unroll
        for (int ci = 0; ci < CIN; ++ci){
            float4 xv = *(const float4*)&XT[ci][e0];
            uint4 wp = *(const uint4*)&WLc[cr][ci][cgrp * 8];
            float wf0 = __uint_as_float(wp.x << 16);
            float wf1 = __uint_as_float(wp.x & 0xFFFF0000u);
            float wf2 = __uint_as_float(wp.y << 16);
            float wf3 = __uint_as_float(wp.y & 0xFFFF0000u);
            float wf4 = __uint_as_float(wp.z << 16);
            float wf5 = __uint_as_float(wp.z & 0xFFFF0000u);
            float wf6 = __uint_as_float(wp.w << 16);
            float wf7 = __uint_as_float(wp.w & 0xFFFF0000u);
            const float xe[4] = { xv.x, xv.y, xv.z, xv.w };
#pragma unroll
            for (int j = 0; j < 4; ++j){
                accC[j][0] += xe[j] * wf0;
                accC[j][1] += xe[j] * wf1;
                accC[j][2] += xe[j] * wf2;
                accC[j][3] += xe[j] * wf3;
                accC[j][4] += xe[j] * wf4;
                accC[j][5] += xe[j] * wf5;
                accC[j][6] += xe[j] * wf6;
                accC[j][7] += xe[j] * wf7;
            }
        }
#pragma unroll
        for (int j = 0; j < 4; ++j){
            float wc = (cr == 0) ? (1.f - fx[j]) * (1.f - fy[j]) :
                       (cr == 1) ? (1.f - fx[j]) * fy[j] :
                       (cr == 2) ? fx[j] * (1.f - fy[j]) :
                                   fx[j] * fy[j];
#pragma unroll
            for (int c = 0; c < 8; ++c) accT[j][c] += wc * accC[j][c];
        }
    }

#pragma unroll
    for (int j = 0; j < 4; ++j){
        if (eid[j] < 0) continue;
        half8 hv;
#pragma unroll
        for (int c = 0; c < 8; ++c) hv[c] = (_Float16)accT[j][c];
        *(half8*)(msg + (size_t)eid[j] * COUT + cgrp * 8) = hv;
    }
}

// --------------------------- final conv (64->2): thread-per-edge, fp16 x rows
__global__ __launch_bounds__(128)
void conv2_msg_k(const _Float16* __restrict__ xh,        // relu(y2) fp16 [NFL][64]
                 const int4* __restrict__ entries,
                 const int* __restrict__ cellOff,
                 const float* __restrict__ Wc,
                 float* __restrict__ msg2)                // [edge][2]
{
    __shared__ float WLf[4][64][2];
    int total = cellOff[NCC];
    int p0 = blockIdx.x * 128;
    if (p0 >= total) return;
    int tid = threadIdx.x;

    int lo = 0, hi = NCC;
    while (hi - lo > 1){ int mid = (lo + hi) >> 1; if (cellOff[mid] <= p0) lo = mid; else hi = mid; }
    const int cell = lo;
    const int kc[4] = { cell, cell + 1, cell + 8, cell + 9 };
#pragma unroll
    for (int c = 0; c < 4; ++c)
        ((float*)&WLf[c][0][0])[tid] = Wc[(size_t)kc[c] * 128 + tid];
    __syncthreads();

    int4 en = entries[p0 + tid];
    if (en.y < 0) return;
    float fx = __int_as_float(en.z), fy = __int_as_float(en.w);
    const _Float16* xp = xh + (size_t)en.x * 64;

    float a[4][2] = {{0.f,0.f},{0.f,0.f},{0.f,0.f},{0.f,0.f}};
#pragma unroll
    for (int ci = 0; ci < 64; ci += 8){
        half8 v = *(const half8*)(xp + ci);
#pragma unroll
        for (int j = 0; j < 8; ++j){
            float xe = (float)v[j];
#pragma unroll
            for (int cr = 0; cr < 4; ++cr){
                a[cr][0] += xe * WLf[cr][ci+j][0];
                a[cr][1] += xe * WLf[cr][ci+j][1];
            }
        }
    }
    float w0 = (1.f-fx)*(1.f-fy), w1 = (1.f-fx)*fy, w2 = fx*(1.f-fy), w3 = fx*fy;
    float m0 = w0*a[0][0] + w1*a[1][0] + w2*a[2][0] + w3*a[3][0];
    float m1 = w0*a[0][1] + w1*a[1][1] + w2*a[2][1] + w3*a[3][1];
    *(float2*)(msg2 + (size_t)en.y * 2) = make_float2(m0, m1);
}

// --------------------------- final combine: thread-per-target, out = .../128
__global__ __launch_bounds__(256)
void final_combine_k(const _Float16* __restrict__ xh,    // relu(y2) fp16 [NFL][64]
                     const float* __restrict__ Wl3, const float* __restrict__ bl3,
                     const float* __restrict__ bc4,
                     const float* __restrict__ msg2,
                     const int* __restrict__ rowptr,
                     float* __restrict__ out)
{
    __shared__ float WS[128];
    int tid = threadIdx.x;
    if (tid < 128) WS[tid] = Wl3[tid];
    __syncthreads();

    int t = blockIdx.x * blockDim.x + tid;
    if (t >= NFL) return;
    int eb = rowptr[t], ee = rowptr[t+1];

    float a0 = bc4[0] + bl3[0];
    float a1 = bc4[1] + bl3[1];
    const _Float16* pr = xh + (size_t)t * 64;
#pragma unroll
    for (int ci = 0; ci < 64; ci += 8){
        half8 v = *(const half8*)(pr + ci);
#pragma unroll
        for (int j = 0; j < 8; ++j){
            float xe = (float)v[j];
            a0 += xe * WS[(ci+j)*2];
            a1 += xe * WS[(ci+j)*2 + 1];
        }
    }
    for (int e = eb; e < ee; ++e){
        float2 m = *(const float2*)(msg2 + (size_t)e * 2);
        a0 += m.x; a1 += m.y;
    }
    out[(size_t)t*2]     = a0 * (1.0f/128.0f);
    out[(size_t)t*2 + 1] = a1 * (1.0f/128.0f);
}

// ---------------- combine0: lin + conv0-msg-sum + FUSED bconv; ansA + xbA ---
__global__ __launch_bounds__(256)
void combine0_k(const float* __restrict__ feat,
                const float* __restrict__ bnd_feat,
                const float* __restrict__ Wl0, const float* __restrict__ bl0,
                const float* __restrict__ bc0,
                const float* __restrict__ Wc1, const float* __restrict__ bc1,
                const EdgeData* __restrict__ edB,
                const int* __restrict__ rowptrB,
                const _Float16* __restrict__ msg,        // [edge][32]
                const int* __restrict__ rowptrF,
                float* __restrict__ ansA,
                _Float16* __restrict__ xbA)              // [NFL][96] relu fp16
{
    int t = blockIdx.x * (blockDim.x >> 6) + (threadIdx.x >> 6);
    if (t >= NFL) return;
    int lane = threadIdx.x & 63;

    if (lane < 32){
        float a = bl0[lane];
#pragma unroll
        for (int ci = 0; ci < 8; ++ci)
            a += feat[t*8 + ci] * Wl0[ci*32 + lane];
        ansA[(size_t)t*96 + lane] = a;
        xbA[(size_t)t*96 + lane]  = (_Float16)frelu(a);

        float b = bc1[lane];
        int eb = rowptrB[t], ee = rowptrB[t+1];
        for (int e = eb; e < ee; ++e){
            EdgeData d = edB[e];
            const float* xp = bnd_feat + (size_t)d.src * 8;
            const float* wp = Wc1 + (size_t)d.ixiy * 256 + lane;
            float t00 = 0.f, t01 = 0.f, t10 = 0.f, t11 = 0.f;
#pragma unroll
            for (int ci = 0; ci < 8; ++ci){
                float xv = xp[ci];
                t00 += xv * wp[ci*32];
                t01 += xv * wp[ci*32 + 256];
                t10 += xv * wp[ci*32 + 2048];
                t11 += xv * wp[ci*32 + 2304];
            }
            float wx1 = d.fx, wy1 = d.fy;
            float wx0 = 1.f - wx1, wy0 = 1.f - wy1;
            b += (wx0*wy0)*t00 + (wx0*wy1)*t01 + (wx1*wy0)*t10 + (wx1*wy1)*t11;
        }
        ansA[(size_t)t*96 + 64 + lane] = b;
        xbA[(size_t)t*96 + 64 + lane]  = (_Float16)frelu(b);
    } else {
        int c = lane - 32;
        float a = bc0[c];
        int eb = rowptrF[t], ee = rowptrF[t+1];
        for (int e = eb; e < ee; ++e)
            a += (float)msg[(size_t)e*32 + c];
        ansA[(size_t)t*96 + 32 + c] = a;
        xbA[(size_t)t*96 + 32 + c]  = (_Float16)frelu(a);
    }
}

// ------- combine: msg-sum + dns (fp16 input) + bias (+resid); y + relu fp16
template<int CIN, bool RESID, bool WRITE_XB>
__global__ __launch_bounds__(256)
void combine12_k(const float* __restrict__ yprev,        // for residual only
                 const _Float16* __restrict__ xprev,     // relu'd fp16 [NFL][CIN]
                 const float* __restrict__ Wl, const float* __restrict__ bl,
                 const float* __restrict__ bc,
                 const _Float16* __restrict__ msg,       // [edge][64]
                 const int* __restrict__ rowptr,
                 float* __restrict__ y,
                 _Float16* __restrict__ xbnext)          // [NFL][64]
{
    int t = blockIdx.x * (blockDim.x >> 6) + (threadIdx.x >> 6);
    if (t >= NFL) return;
    int lane = threadIdx.x & 63;
    int eb = rowptr[t], ee = rowptr[t+1];

    const _Float16* pr = xprev + (size_t)t * CIN;
    float acc = bc[lane] + bl[lane];
#pragma unroll 8
    for (int ci = 0; ci < CIN; ++ci)
        acc += (float)pr[ci] * Wl[ci*64 + lane];
    if (RESID) acc += yprev[(size_t)t*64 + lane];

    for (int e = eb; e < ee; ++e)
        acc += (float)msg[(size_t)e*64 + lane];
    y[(size_t)t*64 + lane] = acc;

    if (WRITE_XB)
        xbnext[(size_t)t*64 + lane] = (_Float16)frelu(acc);
}

// ---------------------------------------------------------------------------
extern "C" void kernel_launch(void* const* d_in, const int* in_sizes, int n_in,
                              void* d_out, int out_size, void* d_ws, size_t ws_size,
                              hipStream_t stream)
{
    const float* fluid_pos  = (const float*)d_in[0];
    const float* bnd_pos    = (const float*)d_in[1];
    const float* fluid_feat = (const float*)d_in[2];
    const float* bnd_feat   = (const float*)d_in[3];
    const int*   f_tgt      = (const int*)  d_in[4];
    const int*   f_src      = (const int*)  d_in[5];
    const int*   b_tgt      = (const int*)  d_in[6];
    const int*   b_src      = (const int*)  d_in[7];
    const float* Wc0 = (const float*)d_in[8];  const float* bc0 = (const float*)d_in[9];
    const float* Wc1 = (const float*)d_in[10]; const float* bc1 = (const float*)d_in[11];
    const float* Wc2 = (const float*)d_in[12]; const float* bc2 = (const float*)d_in[13];
    const float* Wc3 = (const float*)d_in[14]; const float* bc3 = (const float*)d_in[15];
    const float* Wc4 = (const float*)d_in[16]; const float* bc4 = (const float*)d_in[17];
    const float* Wl0 = (const float*)d_in[18]; const float* bl0 = (const float*)d_in[19];
    const float* Wl1 = (const float*)d_in[20]; const float* bl1 = (const float*)d_in[21];
    const float* Wl2 = (const float*)d_in[22]; const float* bl2 = (const float*)d_in[23];
    const float* Wl3 = (const float*)d_in[24]; const float* bl3 = (const float*)d_in[25];

    int nEf = in_sizes[4];
    int nEb = in_sizes[6];
    int entPadMax = nEf + NCC * PADQ;
    float support = (float)sqrt(16.0 / (M_PI * 16384.0));

    int nA = (nEf + 255)/256, nB = (nEb + 255)/256, nC = (NFL + 256)/256;

    char* w = (char*)d_ws;
    auto alloc = [&](size_t bytes){ char* r = w; w += (bytes + 255) & ~(size_t)255; return r; };
    EdgeData* edF      = (EdgeData*)alloc((size_t)nEf * sizeof(EdgeData));
    EdgeData* edB      = (EdgeData*)alloc((size_t)nEb * sizeof(EdgeData));
    int*      hpart    = (int*)     alloc((size_t)nA * 64 * sizeof(int));
    int*      cellOff  = (int*)     alloc(64 * sizeof(int));
    int*      gcursor  = (int*)     alloc(64 * sizeof(int));
    int*      rowptrF  = (int*)     alloc((NFL+1) * sizeof(int));
    int*      rowptrB  = (int*)     alloc((NFL+1) * sizeof(int));
    int4*     entries  = (int4*)    alloc((size_t)entPadMax * sizeof(int4));
    unsigned short* wb0 = (unsigned short*)alloc((size_t)64*8*32 * 2);
    _Float16* wt2      = (_Float16*)alloc((size_t)64*64*96 * 2);  // [cell][cout][k]
    _Float16* wt3      = (_Float16*)alloc((size_t)64*64*64 * 2);
    _Float16* xbA      = (_Float16*)alloc((size_t)NFL*96 * 2);
    _Float16* xb1      = (_Float16*)alloc((size_t)NFL*64 * 2);
    _Float16* xb2      = (_Float16*)alloc((size_t)NFL*64 * 2);
    float*    ansA     = (float*)   alloc((size_t)NFL * 96 * sizeof(float));
    float*    y1       = (float*)   alloc((size_t)NFL * 64 * sizeof(float));
    float*    y2       = (float*)   alloc((size_t)NFL * 64 * sizeof(float));
    _Float16* msg      = (_Float16*)alloc((size_t)nEf * 64 * 2);
    float*    msg2     = (float*)   alloc((size_t)nEf * 2 * sizeof(float));

    // ---- setup: fused prep (edges F/B, partial hists, rowptrs, W-prep)
    setup_k<<<nA + nB + 2*nC + 129, 256, 0, stream>>>(fluid_pos, bnd_pos,
                                                      f_tgt, f_src, nEf,
                                                      b_tgt, b_src, nEb, support,
                                                      edF, edB, hpart, rowptrF, rowptrB,
                                                      Wc2, Wc3, Wc0, wt2, wt3, wb0,
                                                      nA, nB, nC);
    scan_pad_k<<<1, 1024, 0, stream>>>(hpart, nA, cellOff, gcursor, entries);
    scatter_k<<<nA, 256, 0, stream>>>(edF, nEf, cellOff, gcursor, entries);

    int gridM = (entPadMax + PADQ - 1) / PADQ;
    int gridC = (entPadMax + 127) / 128;
    dim3 tgrid(NFL/4);

    // ---- input block
    conv_cell_k<8,32,128,false><<<gridC, 128, 0, stream>>>(fluid_feat, entries, cellOff, wb0, msg);
    combine0_k<<<tgrid, 256, 0, stream>>>(fluid_feat, bnd_feat, Wl0, bl0, bc0,
                                          Wc1, bc1, edB, rowptrB,
                                          msg, rowptrF, ansA, xbA);

    // ---- block 1
    conv_mfma_k<96><<<gridM, 256, 0, stream>>>(xbA, entries, cellOff, wt2, msg);
    combine12_k<96,false,true><<<tgrid, 256, 0, stream>>>(nullptr, xbA, Wl1, bl1, bc2, msg, rowptrF, y1, xb1);

    // ---- block 2
    conv_mfma_k<64><<<gridM, 256, 0, stream>>>(xb1, entries, cellOff, wt3, msg);
    combine12_k<64,true,true><<<tgrid, 256, 0, stream>>>(y1, xb1, Wl2, bl2, bc3, msg, rowptrF, y2, xb2);

    // ---- block 3 (final): thread-per-edge conv + thread-per-target combine
    conv2_msg_k<<<gridC, 128, 0, stream>>>(xb2, entries, cellOff, Wc4, msg2);
    final_combine_k<<<(NFL+255)/256, 256, 0, stream>>>(xb2, Wl3, bl3, bc4, msg2, rowptrF, (float*)d_out);
}